// Round 16
// baseline (369.021 us; speedup 1.0000x reference)
//
#include <hip/hip_runtime.h>
#include <hip/hip_fp8.h>
#include <stdint.h>
#include <cmath>

using f32x4  = __attribute__((ext_vector_type(4)))  float;
using f32x16 = __attribute__((ext_vector_type(16))) float;
using i32x4  = __attribute__((ext_vector_type(4)))  int;
using i32x8  = __attribute__((ext_vector_type(8)))  int;

#define FP8MAX 448.0f

// ---------------------------------------------------------------- helpers
__device__ __forceinline__ uint8_t to_fp8(float v) {
  __hip_fp8_e4m3 q(fminf(fmaxf(v, -FP8MAX), FP8MAX));  // saturating RNE, OCP e4m3fn
  return q.__x;
}

__device__ __forceinline__ uint32_t quant4(float4 v, float s) {
  return (uint32_t)to_fp8(v.x * s) | ((uint32_t)to_fp8(v.y * s) << 8) |
         ((uint32_t)to_fp8(v.z * s) << 16) | ((uint32_t)to_fp8(v.w * s) << 24);
}

// ---------------------------------------------------------------- pass 1: amax(|x|) + fused W-convert
// Blocks 0..(n1/1024-1) also convert W -> fp8 bytes (self-detecting:
// flag 2 = f32 of fp8-exact values; 1 = bf16; 0 = raw fp8 bytes).
// amax slot must be zeroed beforehand (hipMemsetAsync).
__global__ void amax_wconv(const float* __restrict__ x, size_t n4,
                           unsigned int* __restrict__ amax_u,
                           const uint8_t* __restrict__ w,
                           uint8_t* __restrict__ qw, int n1) {
  // ---- W convert part (first n1/1024 blocks)
  if ((int)blockIdx.x * 1024 < n1) {
    const float* wf = (const float*)w;
    const unsigned short* wh = (const unsigned short*)w;
    int f32ok = 1, bf16ok = 1;
    for (int i = threadIdx.x; i < 4096; i += 256) {
      float v = wf[i];
      if (!(isfinite(v) && fabsf(v) <= FP8MAX)) f32ok = 0;
      else { __hip_fp8_e4m3 qq(v); if ((float)qq != v) f32ok = 0; }
      float hv = __uint_as_float(((unsigned int)wh[i]) << 16);
      if (!(isfinite(hv) && fabsf(hv) <= FP8MAX)) bf16ok = 0;
      else { __hip_fp8_e4m3 qh(hv); if ((float)qh != hv) bf16ok = 0; }
    }
    __shared__ int sf, sb;
    if (threadIdx.x == 0) { sf = 1; sb = 1; }
    __syncthreads();
    if (!f32ok) atomicAnd(&sf, 0);
    if (!bf16ok) atomicAnd(&sb, 0);
    __syncthreads();
    unsigned int f = sf ? 2u : (sb ? 1u : 0u);

    int i0 = (blockIdx.x * 256 + threadIdx.x) * 4;
    if (i0 < n1) {
      uint32_t out;
      if (f == 2) {
        float4 v = *(const float4*)((const float*)w + i0);
        out = (uint32_t)to_fp8(v.x) | ((uint32_t)to_fp8(v.y) << 8) |
              ((uint32_t)to_fp8(v.z) << 16) | ((uint32_t)to_fp8(v.w) << 24);
      } else if (f == 1) {
        ushort4 h = *(const ushort4*)((const unsigned short*)w + i0);
        out = (uint32_t)to_fp8(__uint_as_float(((unsigned int)h.x) << 16)) |
              ((uint32_t)to_fp8(__uint_as_float(((unsigned int)h.y) << 16)) << 8) |
              ((uint32_t)to_fp8(__uint_as_float(((unsigned int)h.z) << 16)) << 16) |
              ((uint32_t)to_fp8(__uint_as_float(((unsigned int)h.w) << 16)) << 24);
      } else {
        out = *(const uint32_t*)(w + i0);
      }
      *(uint32_t*)(qw + i0) = out;
    }
  }

  // ---- amax part (all blocks)
  const float4* x4 = (const float4*)x;
  float m = 0.0f;
  size_t stride = (size_t)gridDim.x * blockDim.x;
  for (size_t i = (size_t)blockIdx.x * blockDim.x + threadIdx.x; i < n4; i += stride) {
    float4 v = x4[i];
    m = fmaxf(m, fmaxf(fmaxf(fabsf(v.x), fabsf(v.y)),
                       fmaxf(fabsf(v.z), fabsf(v.w))));
  }
  #pragma unroll
  for (int off = 32; off > 0; off >>= 1)
    m = fmaxf(m, __shfl_xor(m, off));
  __shared__ float sm[16];
  int wid = threadIdx.x >> 6;
  if ((threadIdx.x & 63) == 0) sm[wid] = m;
  __syncthreads();
  if (threadIdx.x == 0) {
    int nw = blockDim.x >> 6;
    float r = sm[0];
    for (int i = 1; i < nw; i++) r = fmaxf(r, sm[i]);
    atomicMax(amax_u, __float_as_uint(r));  // non-negative float bits order-preserving
  }
}

// ---------------------------------------------------------------- pass 2: FUSED quantize + MX-fp8 GEMM, occupancy-first
// One block per 32-row A-strip (grid = M/32).  R15 post-mortem: every pipe
// <30% busy and Occupancy pinned at 22% (8 waves/CU via 64 KB LDS) --
// latency-bound TLP shortage.  Fix: qa 32 KB + launch_bounds(256,4) ->
// 4 blocks/CU x 4 waves = 16 waves/CU; VGPR budget 128 (R15 used 104; this
// version's acc is half the size, ~105 total -- no spill).
//  - A fragments from LDS (conflict-free: row stride 1024B + 16-chunk XOR)
//  - B fragments DIRECT global->VGPR, 1-step register double-buffer
//    (B is 1 MB, L2-resident; latency covered by 16 waves of TLP)
//  - zero barriers / zero inline asm in the main loop (R14 lesson)
// MFMA: mfma_scale_f32_32x32x64_f8f6f4, E8M0 0x7F (=1.0); fragment and
// epilogue mappings verbatim from R8-R15 (verified).
#define SROWS 32

__global__ __launch_bounds__(256, 4) void fused_gemm(
    const float* __restrict__ X,      // [M,1024] fp32
    const uint8_t* __restrict__ B,    // [1024,1024] fp8 (qw)
    float* __restrict__ C,            // [M,1024] f32
    const float* __restrict__ amax_p,
    const float* __restrict__ wscale_p) {
  __shared__ uint8_t qa[SROWS * 1024];  // 32 KB resident A strip (fp8)

  const int t = threadIdx.x;          // 0..255
  const int lane = t & 63;
  const int wave = t >> 6;            // 0..3 (n-column split within n-tile)

  const float amax = fmaxf(amax_p[0], 1e-12f);
  const float scale = FP8MAX / amax;          // reference: FP8_MAX / clip(amax)
  const float s = (1.0f / scale) * wscale_p[0];

  // ---- phase 1: quantize strip into LDS (x strip is contiguous)
  const float4* x4 = (const float4*)(X + (size_t)blockIdx.x * (SROWS * 1024));
  #pragma unroll 4
  for (int i = 0; i < SROWS; ++i) {           // row i, cols t*4..t*4+3
    float4 v = x4[i * 256 + t];               // coalesced
    uint32_t wq = quant4(v, scale);
    int swc = (t >> 2) ^ (i & 15);            // chunk swizzle
    *(uint32_t*)&qa[i * 1024 + swc * 16 + (t & 3) * 4] = wq;
  }
  __syncthreads();                            // qa ready (the ONLY barrier)

  // fragment read constants
  const int lr = lane & 31;           // row-in-fragment (A row == lr)
  const int kh = lane >> 5;           // lane's k-half of the 64-k window
  const int x15 = lr & 15;            // A chunk XOR (row&15 == lr&15)

  // per-lane B base: row wave*64 + lr (j adds 32), k-byte kh*32
  const uint8_t* bbase = B + (size_t)(wave * 64 + lr) * 1024 + kh * 32;

  const size_t c_row0 = (size_t)blockIdx.x * SROWS;

  // ---- loaders (step ss = n*16 + kt, 0..63) — all static indexing
  auto loadB = [&](int ss, i32x8* bf) {
    const uint8_t* p = bbase + (size_t)(ss >> 4) * (256 * 1024) + (ss & 15) * 64;
    #pragma unroll
    for (int j = 0; j < 2; j++) {
      const uint8_t* q = p + (size_t)j * (32 * 1024);
      i32x4 lo = *(const i32x4*)q;
      i32x4 hi = *(const i32x4*)(q + 16);
      bf[j] = (i32x8){lo.x, lo.y, lo.z, lo.w, hi.x, hi.y, hi.z, hi.w};
    }
  };
  auto loadA = [&](int ss, i32x8* af) {
    int cb = (ss & 15) * 4 + kh * 2;
    const uint8_t* p = &qa[lr * 1024];
    i32x4 lo = *(const i32x4*)(p + ((cb    ) ^ x15) * 16);
    i32x4 hi = *(const i32x4*)(p + ((cb + 1) ^ x15) * 16);
    af[0] = (i32x8){lo.x, lo.y, lo.z, lo.w, hi.x, hi.y, hi.z, hi.w};
  };

  f32x16 acc[2] = {};
  i32x8 a0[1], b0[2], a1[1], b1[2];
  loadA(0, a0); loadB(0, b0);

  for (int ss = 0; ss < 64; ss += 2) {
    // prefetch odd step, then compute even step
    loadA(ss + 1, a1); loadB(ss + 1, b1);
    __builtin_amdgcn_s_setprio(1);
    #pragma unroll
    for (int j = 0; j < 2; j++)
      acc[j] = __builtin_amdgcn_mfma_scale_f32_32x32x64_f8f6f4(
          a0[0], b0[j], acc[j], 0, 0, 0, 0x7f7f7f7f, 0, 0x7f7f7f7f);
    __builtin_amdgcn_s_setprio(0);

    // prefetch next even step (clamped redundant load at the end), compute odd
    int s2 = (ss + 2 < 64) ? ss + 2 : 63;
    loadA(s2, a0); loadB(s2, b0);
    __builtin_amdgcn_s_setprio(1);
    #pragma unroll
    for (int j = 0; j < 2; j++)
      acc[j] = __builtin_amdgcn_mfma_scale_f32_32x32x64_f8f6f4(
          a1[0], b1[j], acc[j], 0, 0, 0, 0x7f7f7f7f, 0, 0x7f7f7f7f);
    __builtin_amdgcn_s_setprio(0);

    if (((ss + 1) & 15) == 15) {
      // epilogue (R8-verified): col=lane&31, row=(reg&3)+8*(reg>>2)+4*(lane>>5)
      int n = ss >> 4;
      #pragma unroll
      for (int j = 0; j < 2; j++) {
        size_t row0 = c_row0 + (kh << 2);
        int col = n * 256 + wave * 64 + j * 32 + lr;
        #pragma unroll
        for (int r = 0; r < 16; r++) {
          size_t row = row0 + (r & 3) + ((r >> 2) << 3);
          C[row * 1024 + col] = acc[j][r] * s;
        }
        acc[j] = (f32x16)(0.0f);
      }
    }
  }
}

// ---------------------------------------------------------------- launch
extern "C" void kernel_launch(void* const* d_in, const int* in_sizes, int n_in,
                              void* d_out, int out_size, void* d_ws, size_t ws_size,
                              hipStream_t stream) {
  const float* x = (const float*)d_in[0];
  const uint8_t* wraw = (const uint8_t*)d_in[1];
  const float* wscale = (const float*)d_in[2];
  float* out = (float*)d_out;

  long long in0 = in_sizes[0];   // M*K
  long long in1 = in_sizes[1];   // N*K
  double kd = sqrt((double)in0 * (double)in1 / (double)out_size);
  long long K = (long long)(kd + 0.5);
  long long M = in0 / K;

  // ws layout: [0,4) amax | [4096,+1MB) qw
  unsigned int* amax_u = (unsigned int*)d_ws;
  const float* amax_f = (const float*)d_ws;
  uint8_t* qw = (uint8_t*)d_ws + 4096;

  hipMemsetAsync(d_ws, 0, 4, stream);   // zero amax slot before atomics
  amax_wconv<<<2048, 256, 0, stream>>>(x, (size_t)(in0 / 4), amax_u,
                                       wraw, qw, (int)in1);
  fused_gemm<<<(unsigned)(M / SROWS), 256, 0, stream>>>(x, qw, out,
                                                        amax_f, wscale);
}

// Round 17
// 273.301 us; speedup vs baseline: 1.3502x; 1.3502x over previous
//
#include <hip/hip_runtime.h>
#include <hip/hip_fp8.h>
#include <stdint.h>
#include <cmath>

using f32x4  = __attribute__((ext_vector_type(4)))  float;
using f32x16 = __attribute__((ext_vector_type(16))) float;
using i32x4  = __attribute__((ext_vector_type(4)))  int;
using i32x8  = __attribute__((ext_vector_type(8)))  int;

#define FP8MAX 448.0f

// ---------------------------------------------------------------- helpers
__device__ __forceinline__ void gload_lds16(const void* g, void* l) {
  __builtin_amdgcn_global_load_lds(
      (const __attribute__((address_space(1))) unsigned int*)g,
      (__attribute__((address_space(3))) unsigned int*)l,
      16, 0, 0);
}

__device__ __forceinline__ uint8_t to_fp8(float v) {
  __hip_fp8_e4m3 q(fminf(fmaxf(v, -FP8MAX), FP8MAX));  // saturating RNE, OCP e4m3fn
  return q.__x;
}

__device__ __forceinline__ uint32_t quant4(float4 v, float s) {
  return (uint32_t)to_fp8(v.x * s) | ((uint32_t)to_fp8(v.y * s) << 8) |
         ((uint32_t)to_fp8(v.z * s) << 16) | ((uint32_t)to_fp8(v.w * s) << 24);
}

// ---------------------------------------------------------------- pass 1: amax(|x|) + fused W-convert
// Blocks 0..(n1/1024-1) also convert W -> fp8 bytes (self-detecting:
// flag 2 = f32 of fp8-exact values; 1 = bf16; 0 = raw fp8 bytes).
// amax slot must be zeroed beforehand (hipMemsetAsync).
__global__ void amax_wconv(const float* __restrict__ x, size_t n4,
                           unsigned int* __restrict__ amax_u,
                           const uint8_t* __restrict__ w,
                           uint8_t* __restrict__ qw, int n1) {
  // ---- W convert part (first n1/1024 blocks)
  if ((int)blockIdx.x * 1024 < n1) {
    const float* wf = (const float*)w;
    const unsigned short* wh = (const unsigned short*)w;
    int f32ok = 1, bf16ok = 1;
    for (int i = threadIdx.x; i < 4096; i += 256) {
      float v = wf[i];
      if (!(isfinite(v) && fabsf(v) <= FP8MAX)) f32ok = 0;
      else { __hip_fp8_e4m3 qq(v); if ((float)qq != v) f32ok = 0; }
      float hv = __uint_as_float(((unsigned int)wh[i]) << 16);
      if (!(isfinite(hv) && fabsf(hv) <= FP8MAX)) bf16ok = 0;
      else { __hip_fp8_e4m3 qh(hv); if ((float)qh != hv) bf16ok = 0; }
    }
    __shared__ int sf, sb;
    if (threadIdx.x == 0) { sf = 1; sb = 1; }
    __syncthreads();
    if (!f32ok) atomicAnd(&sf, 0);
    if (!bf16ok) atomicAnd(&sb, 0);
    __syncthreads();
    unsigned int f = sf ? 2u : (sb ? 1u : 0u);

    int i0 = (blockIdx.x * 256 + threadIdx.x) * 4;
    if (i0 < n1) {
      uint32_t out;
      if (f == 2) {
        float4 v = *(const float4*)((const float*)w + i0);
        out = (uint32_t)to_fp8(v.x) | ((uint32_t)to_fp8(v.y) << 8) |
              ((uint32_t)to_fp8(v.z) << 16) | ((uint32_t)to_fp8(v.w) << 24);
      } else if (f == 1) {
        ushort4 h = *(const ushort4*)((const unsigned short*)w + i0);
        out = (uint32_t)to_fp8(__uint_as_float(((unsigned int)h.x) << 16)) |
              ((uint32_t)to_fp8(__uint_as_float(((unsigned int)h.y) << 16)) << 8) |
              ((uint32_t)to_fp8(__uint_as_float(((unsigned int)h.z) << 16)) << 16) |
              ((uint32_t)to_fp8(__uint_as_float(((unsigned int)h.w) << 16)) << 24);
      } else {
        out = *(const uint32_t*)(w + i0);
      }
      *(uint32_t*)(qw + i0) = out;
    }
  }

  // ---- amax part (all blocks)
  const float4* x4 = (const float4*)x;
  float m = 0.0f;
  size_t stride = (size_t)gridDim.x * blockDim.x;
  for (size_t i = (size_t)blockIdx.x * blockDim.x + threadIdx.x; i < n4; i += stride) {
    float4 v = x4[i];
    m = fmaxf(m, fmaxf(fmaxf(fabsf(v.x), fabsf(v.y)),
                       fmaxf(fabsf(v.z), fabsf(v.w))));
  }
  #pragma unroll
  for (int off = 32; off > 0; off >>= 1)
    m = fmaxf(m, __shfl_xor(m, off));
  __shared__ float sm[16];
  int wid = threadIdx.x >> 6;
  if ((threadIdx.x & 63) == 0) sm[wid] = m;
  __syncthreads();
  if (threadIdx.x == 0) {
    int nw = blockDim.x >> 6;
    float r = sm[0];
    for (int i = 1; i < nw; i++) r = fmaxf(r, sm[i]);
    atomicMax(amax_u, __float_as_uint(r));  // non-negative float bits order-preserving
  }
}

// ---------------------------------------------------------------- pass 2: FUSED quantize + MX-fp8 GEMM, R11-pipeline B
// One block per 32-row A-strip (grid = M/32 = 2048).  Strip read ONCE as
// fp32, quantized into a resident 32 KB LDS fp8 tile, then 64 steps
// (4 n-tiles of 256 cols x 16 k-steps of 64):
//  - B coop-staged 16 KB/step via global_load_lds into an NBUF=3 ring
//    (48 KB) with the R11-verified counted-vmcnt schedule: prologue
//    stage(0),stage(1); entry s_waitcnt vmcnt(4) (tail 0) + ONE
//    non-draining barrier; mid-step stage(t+2) (writes buf(t-1), whose
//    readers finished before this step's entry barrier).
//  - A fragment (1x, rows lr) from qa: conflict-free (row stride 1024B,
//    16-chunk XOR).  B fragments (2x) from ring: R12-verified layout.
//  - R16 lesson: coalesced shared staging beats per-lane direct loads;
//    R12 lesson: never drain vmcnt every step.
// LDS 32+48 = 80 KB -> 2 blocks/CU (8 waves).  VGPR ~90, no spill target.
// MFMA: mfma_scale_f32_32x32x64_f8f6f4, E8M0 0x7F (=1.0); fragment and
// epilogue mappings verbatim from R8-R15 (verified).
#define SROWS 32
#define NBUF 3

__global__ __launch_bounds__(256, 2) void fused_gemm(
    const float* __restrict__ X,      // [M,1024] fp32
    const uint8_t* __restrict__ B,    // [1024,1024] fp8 (qw)
    float* __restrict__ C,            // [M,1024] f32
    const float* __restrict__ amax_p,
    const float* __restrict__ wscale_p) {
  __shared__ uint8_t qa[SROWS * 1024];   // 32 KB resident A strip (fp8)
  __shared__ uint8_t qb[NBUF][16384];    // 48 KB B ring (256 rows x 64 B)

  const int t = threadIdx.x;          // 0..255
  const int lane = t & 63;
  const int wave = t >> 6;            // 0..3 (n-column split within n-tile)

  const float amax = fmaxf(amax_p[0], 1e-12f);
  const float scale = FP8MAX / amax;          // reference: FP8_MAX / clip(amax)
  const float s = (1.0f / scale) * wscale_p[0];

  // ---- B staging geometry (verbatim R12): inst p covers row p*64+(t>>2),
  // chunk t&3; LDS linear dest p*4096 + t*16; global chunk pre-swizzled
  // (t&3) ^ ((row>>1)&3) = (t&3) ^ ((t>>3)&3).
  const int gsw = ((t & 3) ^ ((t >> 3) & 3)) * 16;
  const int brow = t >> 2;

  auto stage = [&](int step) {        // step = n*16 + kt
    int nn = step >> 4, kk = step & 15;
    const uint8_t* g = B + (size_t)(nn * 256 + brow) * 1024 + kk * 64 + gsw;
    uint8_t* d = qb[step % NBUF] + t * 16;
    #pragma unroll
    for (int p = 0; p < 4; ++p)
      gload_lds16(g + (size_t)(p * 64) * 1024, d + p * 4096);
  };

  // prologue B stages issue first -> latency hides under phase-1 quant
  stage(0);
  stage(1);

  // ---- phase 1: quantize strip into LDS (x strip is contiguous)
  const float4* x4 = (const float4*)(X + (size_t)blockIdx.x * (SROWS * 1024));
  #pragma unroll 4
  for (int i = 0; i < SROWS; ++i) {           // row i, cols t*4..t*4+3
    float4 v = x4[i * 256 + t];               // coalesced
    uint32_t wq = quant4(v, scale);
    int swc = (t >> 2) ^ (i & 15);            // chunk swizzle
    *(uint32_t*)&qa[i * 1024 + swc * 16 + (t & 3) * 4] = wq;
  }
  __syncthreads();                            // qa ready

  // fragment read constants
  const int lr = lane & 31;           // A row == lr; B row-in-frag
  const int kh = lane >> 5;           // lane's k-half of the 64-k window
  const int x15 = lr & 15;            // A chunk XOR
  const int rsw = (lr >> 1) & 3;      // B chunk XOR
  const int c0b = ((2 * kh) ^ rsw) << 4;
  const int c1b = ((2 * kh + 1) ^ rsw) << 4;

  const size_t c_row0 = (size_t)blockIdx.x * SROWS;

  f32x16 acc[2] = {};

  for (int tt = 0; tt < 64; ++tt) {
    // entry: tile tt's 4 loads landed; tt+1's stay in flight (R11 pattern)
    if (tt + 1 < 64) asm volatile("s_waitcnt vmcnt(4)" ::: "memory");
    else             asm volatile("s_waitcnt vmcnt(0)" ::: "memory");
    __builtin_amdgcn_s_barrier();       // non-draining: cross-wave tile ready
    __builtin_amdgcn_sched_barrier(0);

    const uint8_t* bw = qb[tt % NBUF] + (wave * 64) * 64;  // wave's 64 B-rows
    const int kt = tt & 15;

    i32x8 af, bf[2];
    {
      const uint8_t* p = &qa[lr * 1024];
      int cb = kt * 4 + kh * 2;
      i32x4 lo = *(const i32x4*)(p + ((cb    ) ^ x15) * 16);
      i32x4 hi = *(const i32x4*)(p + ((cb + 1) ^ x15) * 16);
      af = (i32x8){lo.x, lo.y, lo.z, lo.w, hi.x, hi.y, hi.z, hi.w};
    }
    #pragma unroll
    for (int j = 0; j < 2; j++) {
      const uint8_t* p = bw + (j * 32 + lr) * 64;
      i32x4 lo = *(const i32x4*)(p + c0b);
      i32x4 hi = *(const i32x4*)(p + c1b);
      bf[j] = (i32x8){lo.x, lo.y, lo.z, lo.w, hi.x, hi.y, hi.z, hi.w};
    }
    if (tt + 2 < 64) stage(tt + 2);     // writes buf(tt-1): readers done
    asm volatile("s_waitcnt lgkmcnt(0)" ::: "memory");
    __builtin_amdgcn_sched_barrier(0);  // rule #18: fence MFMA below the wait
    __builtin_amdgcn_s_setprio(1);
    #pragma unroll
    for (int j = 0; j < 2; j++)
      acc[j] = __builtin_amdgcn_mfma_scale_f32_32x32x64_f8f6f4(
          af, bf[j], acc[j], 0, 0, 0, 0x7f7f7f7f, 0, 0x7f7f7f7f);
    __builtin_amdgcn_s_setprio(0);

    if (kt == 15) {
      // epilogue (R8-verified): col=lane&31, row=(reg&3)+8*(reg>>2)+4*(lane>>5)
      int n = tt >> 4;
      #pragma unroll
      for (int j = 0; j < 2; j++) {
        size_t row0 = c_row0 + (kh << 2);
        int col = n * 256 + wave * 64 + j * 32 + lr;
        #pragma unroll
        for (int r = 0; r < 16; r++) {
          size_t row = row0 + (r & 3) + ((r >> 2) << 3);
          C[row * 1024 + col] = acc[j][r] * s;
        }
        acc[j] = (f32x16)(0.0f);
      }
    }
  }
}

// ---------------------------------------------------------------- launch
extern "C" void kernel_launch(void* const* d_in, const int* in_sizes, int n_in,
                              void* d_out, int out_size, void* d_ws, size_t ws_size,
                              hipStream_t stream) {
  const float* x = (const float*)d_in[0];
  const uint8_t* wraw = (const uint8_t*)d_in[1];
  const float* wscale = (const float*)d_in[2];
  float* out = (float*)d_out;

  long long in0 = in_sizes[0];   // M*K
  long long in1 = in_sizes[1];   // N*K
  double kd = sqrt((double)in0 * (double)in1 / (double)out_size);
  long long K = (long long)(kd + 0.5);
  long long M = in0 / K;

  // ws layout: [0,4) amax | [4096,+1MB) qw
  unsigned int* amax_u = (unsigned int*)d_ws;
  const float* amax_f = (const float*)d_ws;
  uint8_t* qw = (uint8_t*)d_ws + 4096;

  hipMemsetAsync(d_ws, 0, 4, stream);   // zero amax slot before atomics
  amax_wconv<<<2048, 256, 0, stream>>>(x, (size_t)(in0 / 4), amax_u,
                                       wraw, qw, (int)in1);
  fused_gemm<<<(unsigned)(M / SROWS), 256, 0, stream>>>(x, qw, out,
                                                        amax_f, wscale);
}

// Round 18
// 253.631 us; speedup vs baseline: 1.4550x; 1.0776x over previous
//
#include <hip/hip_runtime.h>
#include <hip/hip_fp8.h>
#include <stdint.h>
#include <cmath>

using f32x4  = __attribute__((ext_vector_type(4)))  float;
using f32x16 = __attribute__((ext_vector_type(16))) float;
using i32x4  = __attribute__((ext_vector_type(4)))  int;
using i32x8  = __attribute__((ext_vector_type(8)))  int;

#define FP8MAX 448.0f

// ---------------------------------------------------------------- helpers
__device__ __forceinline__ uint8_t to_fp8(float v) {
  __hip_fp8_e4m3 q(fminf(fmaxf(v, -FP8MAX), FP8MAX));  // saturating RNE, OCP e4m3fn
  return q.__x;
}

__device__ __forceinline__ uint32_t quant4(float4 v, float s) {
  return (uint32_t)to_fp8(v.x * s) | ((uint32_t)to_fp8(v.y * s) << 8) |
         ((uint32_t)to_fp8(v.z * s) << 16) | ((uint32_t)to_fp8(v.w * s) << 24);
}

// ---------------------------------------------------------------- pass 1: amax(|x|) + fused W-convert
// Blocks 0..(n1/1024-1) also convert W -> fp8 bytes (self-detecting:
// flag 2 = f32 of fp8-exact values; 1 = bf16; 0 = raw fp8 bytes).
// amax slot must be zeroed beforehand (hipMemsetAsync).
__global__ void amax_wconv(const float* __restrict__ x, size_t n4,
                           unsigned int* __restrict__ amax_u,
                           const uint8_t* __restrict__ w,
                           uint8_t* __restrict__ qw, int n1) {
  // ---- W convert part (first n1/1024 blocks)
  if ((int)blockIdx.x * 1024 < n1) {
    const float* wf = (const float*)w;
    const unsigned short* wh = (const unsigned short*)w;
    int f32ok = 1, bf16ok = 1;
    for (int i = threadIdx.x; i < 4096; i += 256) {
      float v = wf[i];
      if (!(isfinite(v) && fabsf(v) <= FP8MAX)) f32ok = 0;
      else { __hip_fp8_e4m3 qq(v); if ((float)qq != v) f32ok = 0; }
      float hv = __uint_as_float(((unsigned int)wh[i]) << 16);
      if (!(isfinite(hv) && fabsf(hv) <= FP8MAX)) bf16ok = 0;
      else { __hip_fp8_e4m3 qh(hv); if ((float)qh != hv) bf16ok = 0; }
    }
    __shared__ int sf, sb;
    if (threadIdx.x == 0) { sf = 1; sb = 1; }
    __syncthreads();
    if (!f32ok) atomicAnd(&sf, 0);
    if (!bf16ok) atomicAnd(&sb, 0);
    __syncthreads();
    unsigned int f = sf ? 2u : (sb ? 1u : 0u);

    int i0 = (blockIdx.x * 256 + threadIdx.x) * 4;
    if (i0 < n1) {
      uint32_t out;
      if (f == 2) {
        float4 v = *(const float4*)((const float*)w + i0);
        out = (uint32_t)to_fp8(v.x) | ((uint32_t)to_fp8(v.y) << 8) |
              ((uint32_t)to_fp8(v.z) << 16) | ((uint32_t)to_fp8(v.w) << 24);
      } else if (f == 1) {
        ushort4 h = *(const ushort4*)((const unsigned short*)w + i0);
        out = (uint32_t)to_fp8(__uint_as_float(((unsigned int)h.x) << 16)) |
              ((uint32_t)to_fp8(__uint_as_float(((unsigned int)h.y) << 16)) << 8) |
              ((uint32_t)to_fp8(__uint_as_float(((unsigned int)h.z) << 16)) << 16) |
              ((uint32_t)to_fp8(__uint_as_float(((unsigned int)h.w) << 16)) << 24);
      } else {
        out = *(const uint32_t*)(w + i0);
      }
      *(uint32_t*)(qw + i0) = out;
    }
  }

  // ---- amax part (all blocks)
  const float4* x4 = (const float4*)x;
  float m = 0.0f;
  size_t stride = (size_t)gridDim.x * blockDim.x;
  for (size_t i = (size_t)blockIdx.x * blockDim.x + threadIdx.x; i < n4; i += stride) {
    float4 v = x4[i];
    m = fmaxf(m, fmaxf(fmaxf(fabsf(v.x), fabsf(v.y)),
                       fmaxf(fabsf(v.z), fabsf(v.w))));
  }
  #pragma unroll
  for (int off = 32; off > 0; off >>= 1)
    m = fmaxf(m, __shfl_xor(m, off));
  __shared__ float sm[16];
  int wid = threadIdx.x >> 6;
  if ((threadIdx.x & 63) == 0) sm[wid] = m;
  __syncthreads();
  if (threadIdx.x == 0) {
    int nw = blockDim.x >> 6;
    float r = sm[0];
    for (int i = 1; i < nw; i++) r = fmaxf(r, sm[i]);
    atomicMax(amax_u, __float_as_uint(r));  // non-negative float bits order-preserving
  }
}

// ---------------------------------------------------------------- pass 2: FUSED quantize + MX-fp8 GEMM, depth-4 B prefetch
// One block per 64-row A-strip (grid = M/64 = 1024, strip order REVERSED so
// early blocks re-read the x-tail the amax pass just left in L3).
// Strip read ONCE as fp32, quantized into a resident 64 KB LDS fp8 tile
// (one barrier), then 64 steps (4 n-tiles x 16 k-steps) with ZERO barriers:
//  - A fragments from LDS, 1-step prefetch (conflict-free: row stride
//    1024B + 16-chunk XOR)  [R15-verified]
//  - B fragments DIRECT global->VGPR with a DEPTH-4 named register ring:
//    loads for step ss+4 issue right after the MFMAs free set ss%4, so a
//    set's use waits vmcnt(12) = ~3 steps (~600cyc) of cover, matching L2
//    latency.  R15's depth-1 gave only ~150cyc -- that was the gap.
//  - no barriers / no inline asm in the loop (R14 lesson); all register
//    sets named + statically indexed (rule #20).
// LDS 64 KB -> 2 blocks/CU (8 waves); VGPR ~185 < 256 (2 waves/SIMD cap).
// MFMA: mfma_scale_f32_32x32x64_f8f6f4, E8M0 0x7F (=1.0); fragment and
// epilogue mappings verbatim from R8-R15 (verified).
#define SROWS 64

__global__ __launch_bounds__(256, 2) void fused_gemm(
    const float* __restrict__ X,      // [M,1024] fp32
    const uint8_t* __restrict__ B,    // [1024,1024] fp8 (qw)
    float* __restrict__ C,            // [M,1024] f32
    const float* __restrict__ amax_p,
    const float* __restrict__ wscale_p,
    int nstrips) {
  __shared__ uint8_t qa[SROWS * 1024];  // 64 KB resident A strip (fp8)

  const int strip = nstrips - 1 - (int)blockIdx.x;   // reversed for L3 hits
  const int t = threadIdx.x;          // 0..255
  const int lane = t & 63;
  const int wave = t >> 6;            // 0..3 (n-column split within n-tile)

  const float amax = fmaxf(amax_p[0], 1e-12f);
  const float scale = FP8MAX / amax;          // reference: FP8_MAX / clip(amax)
  const float s = (1.0f / scale) * wscale_p[0];

  // ---- phase 1: quantize strip into LDS (strip is contiguous in x)
  const float4* x4 = (const float4*)(X + (size_t)strip * (SROWS * 1024));
  #pragma unroll 8
  for (int i = 0; i < SROWS; ++i) {           // row i, cols t*4..t*4+3
    float4 v = x4[i * 256 + t];               // coalesced
    uint32_t wq = quant4(v, scale);
    int swc = (t >> 2) ^ (i & 15);            // chunk swizzle
    *(uint32_t*)&qa[i * 1024 + swc * 16 + (t & 3) * 4] = wq;
  }
  __syncthreads();                            // qa ready (the ONLY barrier)

  // fragment read constants
  const int lr = lane & 31;           // row-in-fragment
  const int kh = lane >> 5;           // lane's k-half of the 64-k window
  const int x15 = lr & 15;            // A chunk XOR (row&15 == lr&15, frags at +32)

  // per-lane B base: row wave*64 + lr (j adds 32), k-byte kh*32
  const uint8_t* bbase = B + (size_t)(wave * 64 + lr) * 1024 + kh * 32;

  const size_t c_row0 = (size_t)strip * SROWS;

  auto loadB = [&](int ss, i32x8* bf) {       // ss pre-clamped by caller
    const uint8_t* p = bbase + (size_t)(ss >> 4) * (256 * 1024) + (ss & 15) * 64;
    #pragma unroll
    for (int j = 0; j < 2; j++) {
      const uint8_t* q = p + (size_t)j * (32 * 1024);
      i32x4 lo = *(const i32x4*)q;
      i32x4 hi = *(const i32x4*)(q + 16);
      bf[j] = (i32x8){lo.x, lo.y, lo.z, lo.w, hi.x, hi.y, hi.z, hi.w};
    }
  };
  auto loadA = [&](int ss, i32x8* af) {
    int cb = (ss & 15) * 4 + kh * 2;
    #pragma unroll
    for (int i = 0; i < 2; i++) {
      const uint8_t* p = &qa[(i * 32 + lr) * 1024];
      i32x4 lo = *(const i32x4*)(p + ((cb    ) ^ x15) * 16);
      i32x4 hi = *(const i32x4*)(p + ((cb + 1) ^ x15) * 16);
      af[i] = (i32x8){lo.x, lo.y, lo.z, lo.w, hi.x, hi.y, hi.z, hi.w};
    }
  };

  f32x16 acc[2][2] = {};
  i32x8 bs0[2], bs1[2], bs2[2], bs3[2];       // depth-4 B register ring
  i32x8 as0[2], as1[2];                       // depth-2 A (LDS) ring

  loadB(0, bs0); loadB(1, bs1); loadB(2, bs2); loadB(3, bs3);
  loadA(0, as0);

  #define GSTEP(SS, ACUR, ANXT, BSET)                                        \
    {                                                                        \
      const int ss_ = (SS);                                                  \
      loadA(ss_ + 1 < 64 ? ss_ + 1 : 63, ANXT);                              \
      __builtin_amdgcn_s_setprio(1);                                         \
      _Pragma("unroll")                                                      \
      for (int i = 0; i < 2; i++)                                            \
        _Pragma("unroll")                                                    \
        for (int j = 0; j < 2; j++)                                          \
          acc[i][j] = __builtin_amdgcn_mfma_scale_f32_32x32x64_f8f6f4(       \
              ACUR[i], BSET[j], acc[i][j], 0, 0, 0, 0x7f7f7f7f, 0, 0x7f7f7f7f); \
      __builtin_amdgcn_s_setprio(0);                                         \
      loadB(ss_ + 4 < 64 ? ss_ + 4 : 63, BSET);                              \
    }

  for (int base = 0; base < 64; base += 4) {
    GSTEP(base + 0, as0, as1, bs0);
    GSTEP(base + 1, as1, as0, bs1);
    GSTEP(base + 2, as0, as1, bs2);
    GSTEP(base + 3, as1, as0, bs3);

    if ((base & 15) == 12) {
      // n-tile finished at ss = base+3; epilogue (R8-verified):
      // col=lane&31, row=(reg&3)+8*(reg>>2)+4*(lane>>5)
      int n = base >> 4;
      #pragma unroll
      for (int i = 0; i < 2; i++) {
        #pragma unroll
        for (int j = 0; j < 2; j++) {
          size_t row0 = c_row0 + i * 32 + (kh << 2);
          int col = n * 256 + wave * 64 + j * 32 + lr;
          #pragma unroll
          for (int r = 0; r < 16; r++) {
            size_t row = row0 + (r & 3) + ((r >> 2) << 3);
            C[row * 1024 + col] = acc[i][j][r] * s;
          }
          acc[i][j] = (f32x16)(0.0f);
        }
      }
    }
  }
  #undef GSTEP
}

// ---------------------------------------------------------------- launch
extern "C" void kernel_launch(void* const* d_in, const int* in_sizes, int n_in,
                              void* d_out, int out_size, void* d_ws, size_t ws_size,
                              hipStream_t stream) {
  const float* x = (const float*)d_in[0];
  const uint8_t* wraw = (const uint8_t*)d_in[1];
  const float* wscale = (const float*)d_in[2];
  float* out = (float*)d_out;

  long long in0 = in_sizes[0];   // M*K
  long long in1 = in_sizes[1];   // N*K
  double kd = sqrt((double)in0 * (double)in1 / (double)out_size);
  long long K = (long long)(kd + 0.5);
  long long M = in0 / K;
  int nstrips = (int)(M / SROWS);

  // ws layout: [0,4) amax | [4096,+1MB) qw
  unsigned int* amax_u = (unsigned int*)d_ws;
  const float* amax_f = (const float*)d_ws;
  uint8_t* qw = (uint8_t*)d_ws + 4096;

  hipMemsetAsync(d_ws, 0, 4, stream);   // zero amax slot before atomics
  amax_wconv<<<2048, 256, 0, stream>>>(x, (size_t)(in0 / 4), amax_u,
                                       wraw, qw, (int)in1);
  fused_gemm<<<(unsigned)nstrips, 256, 0, stream>>>(x, qw, out,
                                                    amax_f, wscale, nstrips);
}